// Round 5
// baseline (144.083 us; speedup 1.0000x reference)
//
#include <hip/hip_runtime.h>

typedef __attribute__((ext_vector_type(8))) short bf16x8;
typedef __attribute__((ext_vector_type(4))) float f32x4;

#define KNBR 32
#define NQ   8          // queries per block (pipelined)

union Frag { int4 i; bf16x8 b; };

__device__ __forceinline__ unsigned short f2bf(float f) {
    unsigned u = __float_as_uint(f);
    u += 0x7FFFu + ((u >> 16) & 1u);          // RNE to bf16
    return (unsigned short)(u >> 16);
}

// one instruction packs two fp32 -> two bf16 (dst.lo = src0, dst.hi = src1)
__device__ __forceinline__ unsigned cvt_pk_bf16(float lo, float hi) {
    unsigned r;
    asm("v_cvt_pk_bf16_f32 %0, %1, %2" : "=v"(r) : "v"(lo), "v"(hi));
    return r;
}

// gelu_tanh(v) = v * sigmoid(2*c0*(v + c1 v^3))  (exactly the tanh form)
__device__ __forceinline__ float fast_gelu(float v) {
    const float c1 = 0.044715f;
    const float n2c0 = -1.5957691216057308f;  // -2*sqrt(2/pi)
    float p = v * fmaf(c1, v * v, 1.0f);
    float e = __expf(n2c0 * p);               // exp(-2u)
    return v * __fdividef(1.0f, 1.0f + e);
}

// k-SLOT REMAP (slot = MFMA contraction index, logical = reference k):
//   slot 0..63  -> edge_in logical k = slot+6   (f_y[0..63], 16B-aligned gathers)
//   slot 64..69 -> edge_in logical k = slot-64  (y0 y1 y2 x0 x1 x2)
//   slot 70..95 -> zero pad
// W1 packed as A-fragments of W1^T with the same slot map:
//   region (mt 0..7, s 0..2), lane l, elem e: row = mt*16+(l&15), slot = s*32+(l>>4)*8+e
// W2 packed as B-fragments with the GEMM2 k-map matching h-in-register layout:
//   region (s 0..3, nt 0..3), lane l, elem e: col = nt*16+(l&15),
//   k = s*32 + (l>>4)*4 + (e&3) + 16*(e>>2)
__global__ __launch_bounds__(256) void pack_weights_kernel(
    const float* __restrict__ W1, const float* __restrict__ W2,
    int4* __restrict__ W1p, int4* __restrict__ W2p)
{
    const int idx = blockIdx.x * 256 + threadIdx.x;
    unsigned short vals[8];
    if (idx < 1536) {                      // 24 regions x 64 lanes
        const int r = idx >> 6, lane = idx & 63;
        const int mt = r / 3, s = r - mt * 3;
        const int row = mt * 16 + (lane & 15), g = lane >> 4;
        #pragma unroll
        for (int e = 0; e < 8; ++e) {
            const int k = s * 32 + g * 8 + e;          // slot index
            float f;
            if      (k < 64) f = W1[(k + 6) * 128 + row];   // f_y features
            else if (k < 70) f = W1[(k - 64) * 128 + row];  // y,x coords
            else             f = 0.0f;
            vals[e] = f2bf(f);
        }
        int4 v;
        v.x = vals[0] | (vals[1] << 16); v.y = vals[2] | (vals[3] << 16);
        v.z = vals[4] | (vals[5] << 16); v.w = vals[6] | (vals[7] << 16);
        W1p[idx] = v;
    } else if (idx < 2560) {               // 16 regions x 64 lanes
        const int i2 = idx - 1536;
        const int r = i2 >> 6, lane = i2 & 63;
        const int s = r >> 2, nt = r & 3;
        const int col = nt * 16 + (lane & 15), g = lane >> 4;
        #pragma unroll
        for (int e = 0; e < 8; ++e) {
            const int k = s * 32 + g * 4 + (e & 3) + 16 * (e >> 2);
            vals[e] = f2bf(W2[k * 64 + col]);
        }
        int4 v;
        v.x = vals[0] | (vals[1] << 16); v.y = vals[2] | (vals[3] << 16);
        v.z = vals[4] | (vals[5] << 16); v.w = vals[6] | (vals[7] << 16);
        W2p[i2] = v;
    }
}

__global__ __launch_bounds__(256) void it_mfma_kernel(
    const float* __restrict__ y,     // [n_in][3]
    const float* __restrict__ xq,    // [n_out][3]
    const float* __restrict__ f_y,   // [n_in][64]
    const float* __restrict__ b1,    // [128]
    const float* __restrict__ b2,    // [64]
    const float* __restrict__ av,    // [128]
    const int*   __restrict__ nbr,   // [n_out*32]
    const int4*  __restrict__ W1p,   // packed W1^T A-fragments (slot map)
    const int4*  __restrict__ W2p,   // packed W2 B-fragments (custom k-map)
    float*       __restrict__ out,   // [n_out][64]
    int n_out)
{
    __shared__ int4  sA1[2][6 * 64];       // double-buffered edge_in^T B-frags
    __shared__ float s_part[4][KNBR];      // per-wave score partials
    __shared__ float s_out[4][64];         // per-wave GEMM2 K-partials

    const int tid = threadIdx.x;
    const int q0  = blockIdx.x * NQ;
    const int w   = tid >> 6;              // wave 0..3
    const int l   = tid & 63;              // lane

    // ---- per-block persistent state: weights, biases (amortized over NQ) ----
    Frag wa[2][3];
    #pragma unroll
    for (int mt = 0; mt < 2; ++mt)
        #pragma unroll
        for (int s = 0; s < 3; ++s)
            wa[mt][s].i = W1p[((2 * w + mt) * 3 + s) * 64 + l];
    Frag b2f[4];
    #pragma unroll
    for (int nto = 0; nto < 4; ++nto)
        b2f[nto].i = W2p[(w * 4 + nto) * 64 + l];

    const int hb = w * 32 + ((l >> 4) << 2);
    float b1a[2][4], ava[2][4];
    *(float4*)&b1a[0][0] = *(const float4*)(b1 + hb);
    *(float4*)&b1a[1][0] = *(const float4*)(b1 + hb + 16);
    *(float4*)&ava[0][0] = *(const float4*)(av + hb);
    *(float4*)&ava[1][0] = *(const float4*)(av + hb + 16);
    const float b2r = (tid < 64) ? b2[tid] : 0.0f;

    // gather lane roles (block-wide, query-independent)
    const int  e  = tid & 31;                    // f_y edge
    const int  c  = tid >> 5;                    // chunk 0..7 (slots 8c..8c+7)
    const int  e2 = tid >> 2;                    // coord edge (valid for coord lanes)
    const bool coord_lane = (tid < 128) && ((tid & 3) == 0);
    const int  fy_slot = ((e >> 4) * 3 + (c >> 2)) * 64 + (e & 15) + 16 * (c & 3);
    const int  co_slot = ((e2 >> 4) * 3 + 2) * 64 + (e2 & 15);

    // ---- prologue: zero pads (both buffers, written once), gather q0 -------
    if (tid < 128 && (tid & 3) != 0) {           // pad slots g=1..3 of region s=2
        const int g = tid & 3;
        int4 z = {0, 0, 0, 0};
        sA1[0][co_slot + 16 * g] = z;
        sA1[1][co_slot + 16 * g] = z;
    }

    int ni_fy = nbr[q0 * KNBR + e];
    int ni_co = coord_lane ? nbr[q0 * KNBR + e2] : 0;
    {
        const float4* f4 = (const float4*)(f_y + (long)ni_fy * 64);
        float4 t0 = f4[c * 2 + 0];
        float4 t1 = f4[c * 2 + 1];
        int4 pk;
        pk.x = cvt_pk_bf16(t0.x, t0.y);
        pk.y = cvt_pk_bf16(t0.z, t0.w);
        pk.z = cvt_pk_bf16(t1.x, t1.y);
        pk.w = cvt_pk_bf16(t1.z, t1.w);
        sA1[0][fy_slot] = pk;
        if (coord_lane) {
            float2 y01 = *(const float2*)(y + ni_co * 3);
            float  yz  = y[ni_co * 3 + 2];
            float2 x01 = *(const float2*)(xq + q0 * 3);
            float  xz  = xq[q0 * 3 + 2];
            int4 pk2 = {0, 0, 0, 0};
            pk2.x = cvt_pk_bf16(y01.x, y01.y);
            pk2.y = cvt_pk_bf16(yz,    x01.x);
            pk2.z = cvt_pk_bf16(x01.y, xz);
            sA1[0][co_slot] = pk2;
        }
    }
    // nbr prefetch for q0+1
    {
        const int qp = (q0 + 1 < n_out) ? q0 + 1 : n_out - 1;
        ni_fy = nbr[qp * KNBR + e];
        ni_co = coord_lane ? nbr[qp * KNBR + e2] : 0;
    }
    __syncthreads();

    const f32x4 zero4 = {0.f, 0.f, 0.f, 0.f};

    #pragma unroll 2
    for (int i = 0; i < NQ; ++i) {
        const int q = q0 + i;
        if (q >= n_out) break;
        const int4* buf = sA1[i & 1];
        const bool have_next = (i < NQ - 1) && (q + 1 < n_out);

        // ---- issue next query's gathers into registers (latency hidden) ----
        float4 nt0, nt1; float2 ny01, nx01; float nyz, nxz;
        if (have_next) {
            const float4* f4n = (const float4*)(f_y + (long)ni_fy * 64);
            nt0 = f4n[c * 2 + 0];
            nt1 = f4n[c * 2 + 1];
            if (coord_lane) {
                ny01 = *(const float2*)(y + ni_co * 3);
                nyz  = y[ni_co * 3 + 2];
                nx01 = *(const float2*)(xq + (q + 1) * 3);
                nxz  = xq[(q + 1) * 3 + 2];
            }
        }
        int ni_fy_nn = 0, ni_co_nn = 0;
        if (i < NQ - 2 && q + 2 < n_out) {
            ni_fy_nn = nbr[(q + 2) * KNBR + e];
            ni_co_nn = coord_lane ? nbr[(q + 2) * KNBR + e2] : 0;
        }

        // ---------- phase 2: GEMM1^T: h^T[hid][edge], wave w -> hid w*32..+31
        f32x4 acc[2][2] = {{zero4, zero4}, {zero4, zero4}};  // [mt][nt]
        #pragma unroll
        for (int s = 0; s < 3; ++s) {
            Frag e0, e1;
            e0.i = buf[(0 * 3 + s) * 64 + l];
            e1.i = buf[(1 * 3 + s) * 64 + l];
            acc[0][0] = __builtin_amdgcn_mfma_f32_16x16x32_bf16(wa[0][s].b, e0.b, acc[0][0], 0, 0, 0);
            acc[0][1] = __builtin_amdgcn_mfma_f32_16x16x32_bf16(wa[0][s].b, e1.b, acc[0][1], 0, 0, 0);
            acc[1][0] = __builtin_amdgcn_mfma_f32_16x16x32_bf16(wa[1][s].b, e0.b, acc[1][0], 0, 0, 0);
            acc[1][1] = __builtin_amdgcn_mfma_f32_16x16x32_bf16(wa[1][s].b, e1.b, acc[1][1], 0, 0, 0);
        }

        // ------ phase 3: bias + gelu (fp32, in-register) + score partials ---
        float h[2][2][4];                      // [mt][nt][r]
        float sc0 = 0.f, sc1 = 0.f;
        #pragma unroll
        for (int mt = 0; mt < 2; ++mt) {
            #pragma unroll
            for (int r = 0; r < 4; ++r) {
                float g0 = fast_gelu(acc[mt][0][r] + b1a[mt][r]);
                float g1 = fast_gelu(acc[mt][1][r] + b1a[mt][r]);
                h[mt][0][r] = g0; h[mt][1][r] = g1;
                sc0 = fmaf(g0, ava[mt][r], sc0);
                sc1 = fmaf(g1, ava[mt][r], sc1);
            }
        }
        sc0 += __shfl_xor(sc0, 16, 64); sc0 += __shfl_xor(sc0, 32, 64);
        sc1 += __shfl_xor(sc1, 16, 64); sc1 += __shfl_xor(sc1, 32, 64);
        if (l < 16) { s_part[w][l] = sc0; s_part[w][l + 16] = sc1; }
        __syncthreads();                                     // B1

        // ---------------- phase 4: softmax (redundant per wave) -------------
        const int e32 = l & 31;
        float sv = s_part[0][e32] + s_part[1][e32] + s_part[2][e32] + s_part[3][e32];
        float mx = sv;
        #pragma unroll
        for (int m = 1; m < 32; m <<= 1) mx = fmaxf(mx, __shfl_xor(mx, m, 64));
        float ex = __expf(sv - mx);
        float sm = ex;
        #pragma unroll
        for (int m = 1; m < 32; m <<= 1) sm += __shfl_xor(sm, m, 64);
        const float alpha = __fdividef(ex, sm);          // lane: alpha[l&31]

        // ------- phase 5: fold alpha into h, pack A2 in-register, GEMM2 -----
        const float al0 = __shfl(alpha, l & 15, 64);
        const float al1 = __shfl(alpha, (l & 15) + 16, 64);
        Frag a2[2];
        a2[0].i.x = cvt_pk_bf16(h[0][0][0] * al0, h[0][0][1] * al0);
        a2[0].i.y = cvt_pk_bf16(h[0][0][2] * al0, h[0][0][3] * al0);
        a2[0].i.z = cvt_pk_bf16(h[1][0][0] * al0, h[1][0][1] * al0);
        a2[0].i.w = cvt_pk_bf16(h[1][0][2] * al0, h[1][0][3] * al0);
        a2[1].i.x = cvt_pk_bf16(h[0][1][0] * al1, h[0][1][1] * al1);
        a2[1].i.y = cvt_pk_bf16(h[0][1][2] * al1, h[0][1][3] * al1);
        a2[1].i.z = cvt_pk_bf16(h[1][1][0] * al1, h[1][1][1] * al1);
        a2[1].i.w = cvt_pk_bf16(h[1][1][2] * al1, h[1][1][3] * al1);

        f32x4 acc2[2][4];
        #pragma unroll
        for (int nto = 0; nto < 4; ++nto) {
            acc2[0][nto] = __builtin_amdgcn_mfma_f32_16x16x32_bf16(a2[0].b, b2f[nto].b, zero4, 0, 0, 0);
            acc2[1][nto] = __builtin_amdgcn_mfma_f32_16x16x32_bf16(a2[1].b, b2f[nto].b, zero4, 0, 0, 0);
        }

        // -------- phase 6: sum over edges (rows) + cross-wave K reduction ---
        #pragma unroll
        for (int nto = 0; nto < 4; ++nto) {
            float o = ((acc2[0][nto][0] + acc2[0][nto][1]) + (acc2[0][nto][2] + acc2[0][nto][3]))
                    + ((acc2[1][nto][0] + acc2[1][nto][1]) + (acc2[1][nto][2] + acc2[1][nto][3]));
            o += __shfl_xor(o, 16, 64);
            o += __shfl_xor(o, 32, 64);
            if (l < 16) s_out[w][l + 16 * nto] = o;
        }
        __syncthreads();                                     // B2
        if (tid < 64)
            out[q * 64 + tid] = s_out[0][tid] + s_out[1][tid]
                              + s_out[2][tid] + s_out[3][tid] + b2r;

        // -------- stage next query's gathers into the other buffer ----------
        if (have_next) {
            int4 pk;
            pk.x = cvt_pk_bf16(nt0.x, nt0.y);
            pk.y = cvt_pk_bf16(nt0.z, nt0.w);
            pk.z = cvt_pk_bf16(nt1.x, nt1.y);
            pk.w = cvt_pk_bf16(nt1.z, nt1.w);
            sA1[(i + 1) & 1][fy_slot] = pk;
            if (coord_lane) {
                int4 pk2 = {0, 0, 0, 0};
                pk2.x = cvt_pk_bf16(ny01.x, ny01.y);
                pk2.y = cvt_pk_bf16(nyz,    nx01.x);
                pk2.z = cvt_pk_bf16(nx01.y, nxz);
                sA1[(i + 1) & 1][co_slot] = pk2;
            }
            __syncthreads();                                 // B3
            ni_fy = ni_fy_nn;
            ni_co = ni_co_nn;
        }
    }
}

extern "C" void kernel_launch(void* const* d_in, const int* in_sizes, int n_in,
                              void* d_out, int out_size, void* d_ws, size_t ws_size,
                              hipStream_t stream) {
    const float* y   = (const float*)d_in[0];
    const float* xq  = (const float*)d_in[1];
    const float* f_y = (const float*)d_in[2];
    const float* W1  = (const float*)d_in[3];
    const float* b1  = (const float*)d_in[4];
    const float* W2  = (const float*)d_in[5];
    const float* b2  = (const float*)d_in[6];
    const float* av  = (const float*)d_in[7];
    const int*   nbr = (const int*)d_in[8];
    float* out = (float*)d_out;

    const int n_out = in_sizes[1] / 3;      // x is [n_out][3]

    int4* W1p = (int4*)d_ws;                // 1536 frags = 24 KB
    int4* W2p = W1p + 1536;                 // 1024 frags = 16 KB

    pack_weights_kernel<<<10, 256, 0, stream>>>(W1, W2, W1p, W2p);
    const int nblk = (n_out + NQ - 1) / NQ;
    it_mfma_kernel<<<nblk, 256, 0, stream>>>(y, xq, f_y, b1, b2, av, nbr,
                                             W1p, W2p, out, n_out);
}

// Round 6
// 114.776 us; speedup vs baseline: 1.2553x; 1.2553x over previous
//
#include <hip/hip_runtime.h>

typedef __attribute__((ext_vector_type(8))) short bf16x8;
typedef __attribute__((ext_vector_type(4))) float f32x4;

#define KNBR 32
#define GQ   2          // queries per wave
#define WAVES 4         // waves per block

union Frag { int4 i; bf16x8 b; };

__device__ __forceinline__ unsigned short f2bf(float f) {
    unsigned u = __float_as_uint(f);
    u += 0x7FFFu + ((u >> 16) & 1u);          // RNE to bf16
    return (unsigned short)(u >> 16);
}

// one instruction packs two fp32 -> two bf16 (dst.lo = src0, dst.hi = src1)
__device__ __forceinline__ unsigned cvt_pk_bf16(float lo, float hi) {
    unsigned r;
    asm("v_cvt_pk_bf16_f32 %0, %1, %2" : "=v"(r) : "v"(lo), "v"(hi));
    return r;
}

// gelu_tanh(v) = v * sigmoid(2*c0*(v + c1 v^3))  (exactly the tanh form)
__device__ __forceinline__ float fast_gelu(float v) {
    const float c1 = 0.044715f;
    const float n2c0 = -1.5957691216057308f;  // -2*sqrt(2/pi)
    float p = v * fmaf(c1, v * v, 1.0f);
    float e = __expf(n2c0 * p);               // exp(-2u)
    return v * __fdividef(1.0f, 1.0f + e);
}

// k-SLOT REMAP (slot = MFMA contraction index, logical = reference k):
//   slot 0..63  -> edge_in logical k = slot+6   (f_y[0..63], 16B-aligned gathers)
//   slot 64..69 -> edge_in logical k = slot-64  (y0 y1 y2 x0 x1 x2)
//   slot 70..95 -> zero pad
// W1 packed as A-fragments of W1^T with the same slot map:
//   region (mt 0..7, s 0..2), lane l, elem e: row = mt*16+(l&15), slot = s*32+(l>>4)*8+e
// W2 packed as B-fragments with the GEMM2 k-map matching h-in-register layout:
//   region (s 0..3, nt 0..3), lane l, elem e: col = nt*16+(l&15),
//   k = s*32 + (l>>4)*4 + (e&3) + 16*(e>>2)
__global__ __launch_bounds__(256) void pack_weights_kernel(
    const float* __restrict__ W1, const float* __restrict__ W2,
    int4* __restrict__ W1p, int4* __restrict__ W2p)
{
    const int idx = blockIdx.x * 256 + threadIdx.x;
    unsigned short vals[8];
    if (idx < 1536) {                      // 24 regions x 64 lanes
        const int r = idx >> 6, lane = idx & 63;
        const int mt = r / 3, s = r - mt * 3;
        const int row = mt * 16 + (lane & 15), g = lane >> 4;
        #pragma unroll
        for (int e = 0; e < 8; ++e) {
            const int k = s * 32 + g * 8 + e;          // slot index
            float f;
            if      (k < 64) f = W1[(k + 6) * 128 + row];   // f_y features
            else if (k < 70) f = W1[(k - 64) * 128 + row];  // y,x coords
            else             f = 0.0f;
            vals[e] = f2bf(f);
        }
        int4 v;
        v.x = vals[0] | (vals[1] << 16); v.y = vals[2] | (vals[3] << 16);
        v.z = vals[4] | (vals[5] << 16); v.w = vals[6] | (vals[7] << 16);
        W1p[idx] = v;
    } else if (idx < 2560) {               // 16 regions x 64 lanes
        const int i2 = idx - 1536;
        const int r = i2 >> 6, lane = i2 & 63;
        const int s = r >> 2, nt = r & 3;
        const int col = nt * 16 + (lane & 15), g = lane >> 4;
        #pragma unroll
        for (int e = 0; e < 8; ++e) {
            const int k = s * 32 + g * 4 + (e & 3) + 16 * (e >> 2);
            vals[e] = f2bf(W2[k * 64 + col]);
        }
        int4 v;
        v.x = vals[0] | (vals[1] << 16); v.y = vals[2] | (vals[3] << 16);
        v.z = vals[4] | (vals[5] << 16); v.w = vals[6] | (vals[7] << 16);
        W2p[i2] = v;
    }
}

__global__ __launch_bounds__(256) void it_mfma_kernel(
    const float* __restrict__ y,     // [n_in][3]
    const float* __restrict__ xq,    // [n_out][3]
    const float* __restrict__ f_y,   // [n_in][64]
    const float* __restrict__ b1,    // [128]
    const float* __restrict__ b2,    // [64]
    const float* __restrict__ av,    // [128]
    const int*   __restrict__ nbr,   // [n_out*32]
    const int4*  __restrict__ Wall,  // W1p (1536) ++ W2p (1024) fragments
    float*       __restrict__ out,   // [n_out][64]
    int n_out)
{
    __shared__ int4 sW[2560];              // 40 KB: W1 frags then W2 frags

    const int tid = threadIdx.x;
    const int w   = tid >> 6;              // wave 0..3
    const int l   = tid & 63;              // lane
    const int l15 = l & 15;
    const int g   = l >> 4;                // quarter-group 0..3

    // ---- prologue (only barrier): stage packed weights into LDS ----
    #pragma unroll
    for (int t = 0; t < 10; ++t)
        sW[tid + t * 256] = Wall[tid + t * 256];
    __syncthreads();
    const int4* sW1 = sW;                  // region (mt*3+s)*64 + lane
    const int4* sW2 = sW + 1536;           // region (s2*4+nto)*64 + lane

    const f32x4 zero4 = {0.f, 0.f, 0.f, 0.f};

    #pragma unroll 1
    for (int i = 0; i < GQ; ++i) {
        const int q = (blockIdx.x * WAVES + w) * GQ + i;
        if (q >= n_out) break;             // after the only barrier: safe

        // ---------- phase 1: gather edge data into per-lane B1 fragments ----
        const int ni0 = nbr[q * KNBR + l15];        // edge l15      (nt=0)
        const int ni1 = nbr[q * KNBR + 16 + l15];   // edge 16+l15   (nt=1)

        Frag B1[2][3];                     // [nt][s]
        {
            const float4* f0 = (const float4*)(f_y + (long)ni0 * 64 + g * 8);
            const float4* f1 = (const float4*)(f_y + (long)ni1 * 64 + g * 8);
            float4 a0 = f0[0], a1 = f0[1];          // s=0: cols g*8..g*8+7
            float4 a2 = f0[8], a3 = f0[9];          // s=1: cols 32+g*8..
            float4 c0 = f1[0], c1 = f1[1];
            float4 c2 = f1[8], c3 = f1[9];
            B1[0][0].i.x = cvt_pk_bf16(a0.x, a0.y);
            B1[0][0].i.y = cvt_pk_bf16(a0.z, a0.w);
            B1[0][0].i.z = cvt_pk_bf16(a1.x, a1.y);
            B1[0][0].i.w = cvt_pk_bf16(a1.z, a1.w);
            B1[0][1].i.x = cvt_pk_bf16(a2.x, a2.y);
            B1[0][1].i.y = cvt_pk_bf16(a2.z, a2.w);
            B1[0][1].i.z = cvt_pk_bf16(a3.x, a3.y);
            B1[0][1].i.w = cvt_pk_bf16(a3.z, a3.w);
            B1[1][0].i.x = cvt_pk_bf16(c0.x, c0.y);
            B1[1][0].i.y = cvt_pk_bf16(c0.z, c0.w);
            B1[1][0].i.z = cvt_pk_bf16(c1.x, c1.y);
            B1[1][0].i.w = cvt_pk_bf16(c1.z, c1.w);
            B1[1][1].i.x = cvt_pk_bf16(c2.x, c2.y);
            B1[1][1].i.y = cvt_pk_bf16(c2.z, c2.w);
            B1[1][1].i.z = cvt_pk_bf16(c3.x, c3.y);
            B1[1][1].i.w = cvt_pk_bf16(c3.z, c3.w);
        }
        // s=2 region: coords in slots 64..69 (group g==0 only), rest zero pad
        B1[0][2].i = make_int4(0, 0, 0, 0);
        B1[1][2].i = make_int4(0, 0, 0, 0);
        if (g == 0) {
            float2 ya = *(const float2*)(y + ni0 * 3);
            float  yaz = y[ni0 * 3 + 2];
            float2 yb = *(const float2*)(y + ni1 * 3);
            float  ybz = y[ni1 * 3 + 2];
            float2 x01 = *(const float2*)(xq + q * 3);
            float  xz  = xq[q * 3 + 2];
            B1[0][2].i.x = cvt_pk_bf16(ya.x, ya.y);
            B1[0][2].i.y = cvt_pk_bf16(yaz,  x01.x);
            B1[0][2].i.z = cvt_pk_bf16(x01.y, xz);
            B1[1][2].i.x = cvt_pk_bf16(yb.x, yb.y);
            B1[1][2].i.y = cvt_pk_bf16(ybz,  x01.x);
            B1[1][2].i.z = cvt_pk_bf16(x01.y, xz);
        }

        // ---------- phase 2+3: GEMM1 (per mt-pair) + gelu + pack A2 ---------
        Frag A2[2][4];                     // [nt][s2]  h as GEMM2 A-fragments
        float sc0 = 0.f, sc1 = 0.f;        // score partials (edges l15, 16+l15)
        #pragma unroll
        for (int j = 0; j < 4; ++j) {      // mt pair (2j, 2j+1)
            f32x4 acc[2][2] = {{zero4, zero4}, {zero4, zero4}};  // [mp][nt]
            #pragma unroll
            for (int s = 0; s < 3; ++s) {
                Frag wa0, wa1;
                wa0.i = sW1[((2 * j + 0) * 3 + s) * 64 + l];
                wa1.i = sW1[((2 * j + 1) * 3 + s) * 64 + l];
                acc[0][0] = __builtin_amdgcn_mfma_f32_16x16x32_bf16(wa0.b, B1[0][s].b, acc[0][0], 0, 0, 0);
                acc[0][1] = __builtin_amdgcn_mfma_f32_16x16x32_bf16(wa0.b, B1[1][s].b, acc[0][1], 0, 0, 0);
                acc[1][0] = __builtin_amdgcn_mfma_f32_16x16x32_bf16(wa1.b, B1[0][s].b, acc[1][0], 0, 0, 0);
                acc[1][1] = __builtin_amdgcn_mfma_f32_16x16x32_bf16(wa1.b, B1[1][s].b, acc[1][1], 0, 0, 0);
            }
            #pragma unroll
            for (int mp = 0; mp < 2; ++mp) {
                const int hbase = (2 * j + mp) * 16 + g * 4;
                float4 b14 = *(const float4*)(b1 + hbase);
                float4 a14 = *(const float4*)(av + hbase);
                float h0[4], h1[4];
                h0[0] = fast_gelu(acc[mp][0][0] + b14.x);
                h0[1] = fast_gelu(acc[mp][0][1] + b14.y);
                h0[2] = fast_gelu(acc[mp][0][2] + b14.z);
                h0[3] = fast_gelu(acc[mp][0][3] + b14.w);
                h1[0] = fast_gelu(acc[mp][1][0] + b14.x);
                h1[1] = fast_gelu(acc[mp][1][1] + b14.y);
                h1[2] = fast_gelu(acc[mp][1][2] + b14.z);
                h1[3] = fast_gelu(acc[mp][1][3] + b14.w);
                sc0 = fmaf(h0[0], a14.x, sc0); sc0 = fmaf(h0[1], a14.y, sc0);
                sc0 = fmaf(h0[2], a14.z, sc0); sc0 = fmaf(h0[3], a14.w, sc0);
                sc1 = fmaf(h1[0], a14.x, sc1); sc1 = fmaf(h1[1], a14.y, sc1);
                sc1 = fmaf(h1[2], a14.z, sc1); sc1 = fmaf(h1[3], a14.w, sc1);
                // A2[nt][j] words: mp=0 -> x,y ; mp=1 -> z,w
                if (mp == 0) {
                    A2[0][j].i.x = cvt_pk_bf16(h0[0], h0[1]);
                    A2[0][j].i.y = cvt_pk_bf16(h0[2], h0[3]);
                    A2[1][j].i.x = cvt_pk_bf16(h1[0], h1[1]);
                    A2[1][j].i.y = cvt_pk_bf16(h1[2], h1[3]);
                } else {
                    A2[0][j].i.z = cvt_pk_bf16(h0[0], h0[1]);
                    A2[0][j].i.w = cvt_pk_bf16(h0[2], h0[3]);
                    A2[1][j].i.z = cvt_pk_bf16(h1[0], h1[1]);
                    A2[1][j].i.w = cvt_pk_bf16(h1[2], h1[3]);
                }
            }
        }

        // ---------- phase 4: in-wave softmax over 32 edges -------------------
        sc0 += __shfl_xor(sc0, 16, 64); sc0 += __shfl_xor(sc0, 32, 64);
        sc1 += __shfl_xor(sc1, 16, 64); sc1 += __shfl_xor(sc1, 32, 64);
        float mx = fmaxf(sc0, sc1);
        mx = fmaxf(mx, __shfl_xor(mx, 1, 64));
        mx = fmaxf(mx, __shfl_xor(mx, 2, 64));
        mx = fmaxf(mx, __shfl_xor(mx, 4, 64));
        mx = fmaxf(mx, __shfl_xor(mx, 8, 64));
        float ex0 = __expf(sc0 - mx);
        float ex1 = __expf(sc1 - mx);
        float sm = ex0 + ex1;
        sm += __shfl_xor(sm, 1, 64);
        sm += __shfl_xor(sm, 2, 64);
        sm += __shfl_xor(sm, 4, 64);
        sm += __shfl_xor(sm, 8, 64);
        const float inv = __fdividef(1.0f, sm);
        const float al0 = ex0 * inv;       // alpha[edge l15]
        const float al1 = ex1 * inv;       // alpha[edge 16+l15]

        // ---------- phase 5: GEMM2, K=128 in one wave ------------------------
        f32x4 acc2[2][4] = {{zero4, zero4, zero4, zero4},
                            {zero4, zero4, zero4, zero4}};   // [nt][nto]
        #pragma unroll
        for (int s2 = 0; s2 < 4; ++s2) {
            #pragma unroll
            for (int nto = 0; nto < 4; ++nto) {
                Frag wb;
                wb.i = sW2[(s2 * 4 + nto) * 64 + l];
                acc2[0][nto] = __builtin_amdgcn_mfma_f32_16x16x32_bf16(A2[0][s2].b, wb.b, acc2[0][nto], 0, 0, 0);
                acc2[1][nto] = __builtin_amdgcn_mfma_f32_16x16x32_bf16(A2[1][s2].b, wb.b, acc2[1][nto], 0, 0, 0);
            }
        }

        // ---------- phase 6: alpha-weighted edge reduce (fp32) + store -------
        float ar0[4], ar1[4];              // alpha for C rows g*4+r (per nt)
        #pragma unroll
        for (int r = 0; r < 4; ++r) {
            ar0[r] = __shfl(al0, g * 4 + r, 64);
            ar1[r] = __shfl(al1, g * 4 + r, 64);
        }
        #pragma unroll
        for (int nto = 0; nto < 4; ++nto) {
            float o = 0.f;
            #pragma unroll
            for (int r = 0; r < 4; ++r) {
                o = fmaf(ar0[r], acc2[0][nto][r], o);
                o = fmaf(ar1[r], acc2[1][nto][r], o);
            }
            o += __shfl_xor(o, 16, 64);
            o += __shfl_xor(o, 32, 64);
            if (l < 16)
                out[q * 64 + nto * 16 + l] = o + b2[nto * 16 + l];
        }
    }
}

extern "C" void kernel_launch(void* const* d_in, const int* in_sizes, int n_in,
                              void* d_out, int out_size, void* d_ws, size_t ws_size,
                              hipStream_t stream) {
    const float* y   = (const float*)d_in[0];
    const float* xq  = (const float*)d_in[1];
    const float* f_y = (const float*)d_in[2];
    const float* W1  = (const float*)d_in[3];
    const float* b1  = (const float*)d_in[4];
    const float* W2  = (const float*)d_in[5];
    const float* b2  = (const float*)d_in[6];
    const float* av  = (const float*)d_in[7];
    const int*   nbr = (const int*)d_in[8];
    float* out = (float*)d_out;

    const int n_out = in_sizes[1] / 3;      // x is [n_out][3]

    int4* W1p = (int4*)d_ws;                // 1536 frags = 24 KB
    int4* W2p = W1p + 1536;                 // 1024 frags = 16 KB (contiguous)

    pack_weights_kernel<<<10, 256, 0, stream>>>(W1, W2, W1p, W2p);
    const int qpb = WAVES * GQ;             // queries per block
    const int nblk = (n_out + qpb - 1) / qpb;
    it_mfma_kernel<<<nblk, 256, 0, stream>>>(y, xq, f_y, b1, b2, av, nbr,
                                             W1p, out, n_out);
}

// Round 7
// 114.465 us; speedup vs baseline: 1.2588x; 1.0027x over previous
//
#include <hip/hip_runtime.h>

typedef __attribute__((ext_vector_type(8))) short bf16x8;
typedef __attribute__((ext_vector_type(4))) float f32x4;

#define KNBR 32
#define WAVES 8         // waves per block, one query per wave

union Frag { int4 i; bf16x8 b; };

__device__ __forceinline__ unsigned short f2bf(float f) {
    unsigned u = __float_as_uint(f);
    u += 0x7FFFu + ((u >> 16) & 1u);          // RNE to bf16
    return (unsigned short)(u >> 16);
}

// one instruction packs two fp32 -> two bf16 (dst.lo = src0, dst.hi = src1)
__device__ __forceinline__ unsigned cvt_pk_bf16(float lo, float hi) {
    unsigned r;
    asm("v_cvt_pk_bf16_f32 %0, %1, %2" : "=v"(r) : "v"(lo), "v"(hi));
    return r;
}

// gelu_tanh(v) = v * sigmoid(2*c0*(v + c1 v^3))  (exactly the tanh form)
// exp folded to v_exp_f32 (2^x) with log2(e) pre-multiplied into the constant.
__device__ __forceinline__ float fast_gelu(float v) {
    const float c1 = 0.044715f;
    const float K2 = -2.3022081951f;          // -2*sqrt(2/pi)*log2(e)
    float p = v * fmaf(c1, v * v, 1.0f);
    float e, r;
    asm("v_exp_f32 %0, %1" : "=v"(e) : "v"(K2 * p));  // e = exp(-2u)
    float d = 1.0f + e;
    asm("v_rcp_f32 %0, %1" : "=v"(r) : "v"(d));
    return v * r;
}

// k-SLOT REMAP (slot = MFMA contraction index, logical = reference k):
//   slot 0..63  -> edge_in logical k = slot+6   (f_y[0..63], 16B-aligned gathers)
//   slot 64..69 -> edge_in logical k = slot-64  (y0 y1 y2 x0 x1 x2)
//   slot 70..95 -> zero pad
// W1 packed as A-fragments of W1^T with the same slot map:
//   region (mt 0..7, s 0..2), lane l, elem e: row = mt*16+(l&15), slot = s*32+(l>>4)*8+e
// W2 packed as B-fragments with the GEMM2 k-map matching h-in-register layout:
//   region (s 0..3, nt 0..3), lane l, elem e: col = nt*16+(l&15),
//   k = s*32 + (l>>4)*4 + (e&3) + 16*(e>>2)
__global__ __launch_bounds__(256) void pack_weights_kernel(
    const float* __restrict__ W1, const float* __restrict__ W2,
    int4* __restrict__ W1p, int4* __restrict__ W2p)
{
    const int idx = blockIdx.x * 256 + threadIdx.x;
    unsigned short vals[8];
    if (idx < 1536) {                      // 24 regions x 64 lanes
        const int r = idx >> 6, lane = idx & 63;
        const int mt = r / 3, s = r - mt * 3;
        const int row = mt * 16 + (lane & 15), g = lane >> 4;
        #pragma unroll
        for (int e = 0; e < 8; ++e) {
            const int k = s * 32 + g * 8 + e;          // slot index
            float f;
            if      (k < 64) f = W1[(k + 6) * 128 + row];   // f_y features
            else if (k < 70) f = W1[(k - 64) * 128 + row];  // y,x coords
            else             f = 0.0f;
            vals[e] = f2bf(f);
        }
        int4 v;
        v.x = vals[0] | (vals[1] << 16); v.y = vals[2] | (vals[3] << 16);
        v.z = vals[4] | (vals[5] << 16); v.w = vals[6] | (vals[7] << 16);
        W1p[idx] = v;
    } else if (idx < 2560) {               // 16 regions x 64 lanes
        const int i2 = idx - 1536;
        const int r = i2 >> 6, lane = i2 & 63;
        const int s = r >> 2, nt = r & 3;
        const int col = nt * 16 + (lane & 15), g = lane >> 4;
        #pragma unroll
        for (int e = 0; e < 8; ++e) {
            const int k = s * 32 + g * 4 + (e & 3) + 16 * (e >> 2);
            vals[e] = f2bf(W2[k * 64 + col]);
        }
        int4 v;
        v.x = vals[0] | (vals[1] << 16); v.y = vals[2] | (vals[3] << 16);
        v.z = vals[4] | (vals[5] << 16); v.w = vals[6] | (vals[7] << 16);
        W2p[i2] = v;
    }
}

__global__ __launch_bounds__(512, 8) void it_mfma_kernel(
    const float* __restrict__ y,     // [n_in][3]
    const float* __restrict__ xq,    // [n_out][3]
    const float* __restrict__ f_y,   // [n_in][64]
    const float* __restrict__ b1,    // [128]
    const float* __restrict__ b2,    // [64]
    const float* __restrict__ av,    // [128]
    const int*   __restrict__ nbr,   // [n_out*32]
    const int4*  __restrict__ Wall,  // W1p (1536) ++ W2p (1024) fragments
    float*       __restrict__ out,   // [n_out][64]
    int n_out)
{
    __shared__ int4 sW[2560];              // 40 KB: W1 frags then W2 frags

    const int tid = threadIdx.x;
    const int w   = tid >> 6;              // wave 0..7
    const int l   = tid & 63;              // lane
    const int l15 = l & 15;
    const int g   = l >> 4;                // quarter-group 0..3

    // ---- prologue (only barrier): stage packed weights into LDS ----
    #pragma unroll
    for (int t = 0; t < 5; ++t)
        sW[tid + t * 512] = Wall[tid + t * 512];
    __syncthreads();
    const int4* sW1 = sW;                  // region (mt*3+s)*64 + lane
    const int4* sW2 = sW + 1536;           // region (s2*4+nto)*64 + lane

    const f32x4 zero4 = {0.f, 0.f, 0.f, 0.f};

    const int q = blockIdx.x * WAVES + w;  // one query per wave
    if (q >= n_out) return;                // after the only barrier: safe

    // ---------- phase 1: gather edge data into per-lane B1 fragments ----
    const int ni0 = nbr[q * KNBR + l15];        // edge l15      (nt=0)
    const int ni1 = nbr[q * KNBR + 16 + l15];   // edge 16+l15   (nt=1)

    Frag B1[2][3];                     // [nt][s]
    {
        const float4* f0 = (const float4*)(f_y + (long)ni0 * 64 + g * 8);
        const float4* f1 = (const float4*)(f_y + (long)ni1 * 64 + g * 8);
        float4 a0 = f0[0], a1 = f0[1];          // s=0: cols g*8..g*8+7
        float4 a2 = f0[8], a3 = f0[9];          // s=1: cols 32+g*8..
        float4 c0 = f1[0], c1 = f1[1];
        float4 c2 = f1[8], c3 = f1[9];
        B1[0][0].i.x = cvt_pk_bf16(a0.x, a0.y);
        B1[0][0].i.y = cvt_pk_bf16(a0.z, a0.w);
        B1[0][0].i.z = cvt_pk_bf16(a1.x, a1.y);
        B1[0][0].i.w = cvt_pk_bf16(a1.z, a1.w);
        B1[0][1].i.x = cvt_pk_bf16(a2.x, a2.y);
        B1[0][1].i.y = cvt_pk_bf16(a2.z, a2.w);
        B1[0][1].i.z = cvt_pk_bf16(a3.x, a3.y);
        B1[0][1].i.w = cvt_pk_bf16(a3.z, a3.w);
        B1[1][0].i.x = cvt_pk_bf16(c0.x, c0.y);
        B1[1][0].i.y = cvt_pk_bf16(c0.z, c0.w);
        B1[1][0].i.z = cvt_pk_bf16(c1.x, c1.y);
        B1[1][0].i.w = cvt_pk_bf16(c1.z, c1.w);
        B1[1][1].i.x = cvt_pk_bf16(c2.x, c2.y);
        B1[1][1].i.y = cvt_pk_bf16(c2.z, c2.w);
        B1[1][1].i.z = cvt_pk_bf16(c3.x, c3.y);
        B1[1][1].i.w = cvt_pk_bf16(c3.z, c3.w);
    }
    // s=2 region: coords in slots 64..69 (group g==0 only), rest zero pad
    B1[0][2].i = make_int4(0, 0, 0, 0);
    B1[1][2].i = make_int4(0, 0, 0, 0);
    if (g == 0) {
        float2 ya = *(const float2*)(y + ni0 * 3);
        float  yaz = y[ni0 * 3 + 2];
        float2 yb = *(const float2*)(y + ni1 * 3);
        float  ybz = y[ni1 * 3 + 2];
        float2 x01 = *(const float2*)(xq + q * 3);
        float  xz  = xq[q * 3 + 2];
        B1[0][2].i.x = cvt_pk_bf16(ya.x, ya.y);
        B1[0][2].i.y = cvt_pk_bf16(yaz,  x01.x);
        B1[0][2].i.z = cvt_pk_bf16(x01.y, xz);
        B1[1][2].i.x = cvt_pk_bf16(yb.x, yb.y);
        B1[1][2].i.y = cvt_pk_bf16(ybz,  x01.x);
        B1[1][2].i.z = cvt_pk_bf16(x01.y, xz);
    }

    // ---------- phase 2+3: GEMM1 (per mt-pair) + gelu + pack A2 ---------
    Frag A2[2][4];                     // [nt][s2]  h as GEMM2 A-fragments
    float sc0 = 0.f, sc1 = 0.f;        // score partials (edges l15, 16+l15)
    #pragma unroll
    for (int j = 0; j < 4; ++j) {      // mt pair (2j, 2j+1)
        f32x4 acc[2][2] = {{zero4, zero4}, {zero4, zero4}};  // [mp][nt]
        #pragma unroll
        for (int s = 0; s < 3; ++s) {
            Frag wa0, wa1;
            wa0.i = sW1[((2 * j + 0) * 3 + s) * 64 + l];
            wa1.i = sW1[((2 * j + 1) * 3 + s) * 64 + l];
            acc[0][0] = __builtin_amdgcn_mfma_f32_16x16x32_bf16(wa0.b, B1[0][s].b, acc[0][0], 0, 0, 0);
            acc[0][1] = __builtin_amdgcn_mfma_f32_16x16x32_bf16(wa0.b, B1[1][s].b, acc[0][1], 0, 0, 0);
            acc[1][0] = __builtin_amdgcn_mfma_f32_16x16x32_bf16(wa1.b, B1[0][s].b, acc[1][0], 0, 0, 0);
            acc[1][1] = __builtin_amdgcn_mfma_f32_16x16x32_bf16(wa1.b, B1[1][s].b, acc[1][1], 0, 0, 0);
        }
        #pragma unroll
        for (int mp = 0; mp < 2; ++mp) {
            const int hbase = (2 * j + mp) * 16 + g * 4;
            float4 b14 = *(const float4*)(b1 + hbase);
            float4 a14 = *(const float4*)(av + hbase);
            float h0[4], h1[4];
            h0[0] = fast_gelu(acc[mp][0][0] + b14.x);
            h0[1] = fast_gelu(acc[mp][0][1] + b14.y);
            h0[2] = fast_gelu(acc[mp][0][2] + b14.z);
            h0[3] = fast_gelu(acc[mp][0][3] + b14.w);
            h1[0] = fast_gelu(acc[mp][1][0] + b14.x);
            h1[1] = fast_gelu(acc[mp][1][1] + b14.y);
            h1[2] = fast_gelu(acc[mp][1][2] + b14.z);
            h1[3] = fast_gelu(acc[mp][1][3] + b14.w);
            sc0 = fmaf(h0[0], a14.x, sc0); sc0 = fmaf(h0[1], a14.y, sc0);
            sc0 = fmaf(h0[2], a14.z, sc0); sc0 = fmaf(h0[3], a14.w, sc0);
            sc1 = fmaf(h1[0], a14.x, sc1); sc1 = fmaf(h1[1], a14.y, sc1);
            sc1 = fmaf(h1[2], a14.z, sc1); sc1 = fmaf(h1[3], a14.w, sc1);
            // A2[nt][j] words: mp=0 -> x,y ; mp=1 -> z,w
            if (mp == 0) {
                A2[0][j].i.x = cvt_pk_bf16(h0[0], h0[1]);
                A2[0][j].i.y = cvt_pk_bf16(h0[2], h0[3]);
                A2[1][j].i.x = cvt_pk_bf16(h1[0], h1[1]);
                A2[1][j].i.y = cvt_pk_bf16(h1[2], h1[3]);
            } else {
                A2[0][j].i.z = cvt_pk_bf16(h0[0], h0[1]);
                A2[0][j].i.w = cvt_pk_bf16(h0[2], h0[3]);
                A2[1][j].i.z = cvt_pk_bf16(h1[0], h1[1]);
                A2[1][j].i.w = cvt_pk_bf16(h1[2], h1[3]);
            }
        }
    }

    // ---------- phase 4: in-wave softmax over 32 edges -------------------
    sc0 += __shfl_xor(sc0, 16, 64); sc0 += __shfl_xor(sc0, 32, 64);
    sc1 += __shfl_xor(sc1, 16, 64); sc1 += __shfl_xor(sc1, 32, 64);
    float mx = fmaxf(sc0, sc1);
    mx = fmaxf(mx, __shfl_xor(mx, 1, 64));
    mx = fmaxf(mx, __shfl_xor(mx, 2, 64));
    mx = fmaxf(mx, __shfl_xor(mx, 4, 64));
    mx = fmaxf(mx, __shfl_xor(mx, 8, 64));
    float ex0 = __expf(sc0 - mx);
    float ex1 = __expf(sc1 - mx);
    float sm = ex0 + ex1;
    sm += __shfl_xor(sm, 1, 64);
    sm += __shfl_xor(sm, 2, 64);
    sm += __shfl_xor(sm, 4, 64);
    sm += __shfl_xor(sm, 8, 64);
    const float inv = __fdividef(1.0f, sm);
    const float al0 = ex0 * inv;       // alpha[edge l15]
    const float al1 = ex1 * inv;       // alpha[edge 16+l15]

    // ---------- phase 5: GEMM2, K=128 in one wave ------------------------
    f32x4 acc2[2][4] = {{zero4, zero4, zero4, zero4},
                        {zero4, zero4, zero4, zero4}};   // [nt][nto]
    #pragma unroll
    for (int s2 = 0; s2 < 4; ++s2) {
        #pragma unroll
        for (int nto = 0; nto < 4; ++nto) {
            Frag wb;
            wb.i = sW2[(s2 * 4 + nto) * 64 + l];
            acc2[0][nto] = __builtin_amdgcn_mfma_f32_16x16x32_bf16(A2[0][s2].b, wb.b, acc2[0][nto], 0, 0, 0);
            acc2[1][nto] = __builtin_amdgcn_mfma_f32_16x16x32_bf16(A2[1][s2].b, wb.b, acc2[1][nto], 0, 0, 0);
        }
    }

    // ---------- phase 6: alpha-weighted edge reduce (fp32) + store -------
    float ar0[4], ar1[4];              // alpha for C rows g*4+r (per nt)
    #pragma unroll
    for (int r = 0; r < 4; ++r) {
        ar0[r] = __shfl(al0, g * 4 + r, 64);
        ar1[r] = __shfl(al1, g * 4 + r, 64);
    }
    #pragma unroll
    for (int nto = 0; nto < 4; ++nto) {
        float o = 0.f;
        #pragma unroll
        for (int r = 0; r < 4; ++r) {
            o = fmaf(ar0[r], acc2[0][nto][r], o);
            o = fmaf(ar1[r], acc2[1][nto][r], o);
        }
        o += __shfl_xor(o, 16, 64);
        o += __shfl_xor(o, 32, 64);
        if (l < 16)
            out[q * 64 + nto * 16 + l] = o + b2[nto * 16 + l];
    }
}

extern "C" void kernel_launch(void* const* d_in, const int* in_sizes, int n_in,
                              void* d_out, int out_size, void* d_ws, size_t ws_size,
                              hipStream_t stream) {
    const float* y   = (const float*)d_in[0];
    const float* xq  = (const float*)d_in[1];
    const float* f_y = (const float*)d_in[2];
    const float* W1  = (const float*)d_in[3];
    const float* b1  = (const float*)d_in[4];
    const float* W2  = (const float*)d_in[5];
    const float* b2  = (const float*)d_in[6];
    const float* av  = (const float*)d_in[7];
    const int*   nbr = (const int*)d_in[8];
    float* out = (float*)d_out;

    const int n_out = in_sizes[1] / 3;      // x is [n_out][3]

    int4* W1p = (int4*)d_ws;                // 1536 frags = 24 KB
    int4* W2p = W1p + 1536;                 // 1024 frags = 16 KB (contiguous)

    pack_weights_kernel<<<10, 256, 0, stream>>>(W1, W2, W1p, W2p);
    const int nblk = (n_out + WAVES - 1) / WAVES;
    it_mfma_kernel<<<nblk, 512, 0, stream>>>(y, xq, f_y, b1, b2, av, nbr,
                                             W1p, out, n_out);
}

// Round 8
// 76.159 us; speedup vs baseline: 1.8919x; 1.5030x over previous
//
#include <hip/hip_runtime.h>

typedef __attribute__((ext_vector_type(8))) short bf16x8;
typedef __attribute__((ext_vector_type(4))) float f32x4;

#define KNBR 32
#define WAVES 8         // waves per block, one query per wave

union Frag { int4 i; bf16x8 b; };

__device__ __forceinline__ unsigned short f2bf(float f) {
    unsigned u = __float_as_uint(f);
    u += 0x7FFFu + ((u >> 16) & 1u);          // RNE to bf16
    return (unsigned short)(u >> 16);
}

// one instruction packs two fp32 -> two bf16 (dst.lo = src0, dst.hi = src1)
__device__ __forceinline__ unsigned cvt_pk_bf16(float lo, float hi) {
    unsigned r;
    asm("v_cvt_pk_bf16_f32 %0, %1, %2" : "=v"(r) : "v"(lo), "v"(hi));
    return r;
}

// gelu_tanh(v) = v * sigmoid(2*c0*(v + c1 v^3))  (exactly the tanh form)
// exp folded to v_exp_f32 (2^x) with log2(e) pre-multiplied into the constant.
__device__ __forceinline__ float fast_gelu(float v) {
    const float c1 = 0.044715f;
    const float K2 = -2.3022081951f;          // -2*sqrt(2/pi)*log2(e)
    float p = v * fmaf(c1, v * v, 1.0f);
    float e, r;
    asm("v_exp_f32 %0, %1" : "=v"(e) : "v"(K2 * p));  // e = exp(-2u)
    float d = 1.0f + e;
    asm("v_rcp_f32 %0, %1" : "=v"(r) : "v"(d));
    return v * r;
}

// k-SLOT REMAP (slot = MFMA contraction index, logical = reference k):
//   slot 0..63  -> edge_in logical k = slot+6   (f_y[0..63], 16B-aligned gathers)
//   slot 64..69 -> edge_in logical k = slot-64  (y0 y1 y2 x0 x1 x2)
//   slot 70..95 -> zero pad
// W1 packed as A-fragments of W1^T with the same slot map:
//   region (mt 0..7, s 0..2), lane l, elem e: row = mt*16+(l&15), slot = s*32+(l>>4)*8+e
// W2 packed as B-fragments with the GEMM2 k-map matching h-in-register layout:
//   region (s 0..3, nt 0..3), lane l, elem e: col = nt*16+(l&15),
//   k = s*32 + (l>>4)*4 + (e&3) + 16*(e>>2)
__global__ __launch_bounds__(256) void pack_weights_kernel(
    const float* __restrict__ W1, const float* __restrict__ W2,
    int4* __restrict__ W1p, int4* __restrict__ W2p)
{
    const int idx = blockIdx.x * 256 + threadIdx.x;
    unsigned short vals[8];
    if (idx < 1536) {                      // 24 regions x 64 lanes
        const int r = idx >> 6, lane = idx & 63;
        const int mt = r / 3, s = r - mt * 3;
        const int row = mt * 16 + (lane & 15), g = lane >> 4;
        #pragma unroll
        for (int e = 0; e < 8; ++e) {
            const int k = s * 32 + g * 8 + e;          // slot index
            float f;
            if      (k < 64) f = W1[(k + 6) * 128 + row];   // f_y features
            else if (k < 70) f = W1[(k - 64) * 128 + row];  // y,x coords
            else             f = 0.0f;
            vals[e] = f2bf(f);
        }
        int4 v;
        v.x = vals[0] | (vals[1] << 16); v.y = vals[2] | (vals[3] << 16);
        v.z = vals[4] | (vals[5] << 16); v.w = vals[6] | (vals[7] << 16);
        W1p[idx] = v;
    } else if (idx < 2560) {               // 16 regions x 64 lanes
        const int i2 = idx - 1536;
        const int r = i2 >> 6, lane = i2 & 63;
        const int s = r >> 2, nt = r & 3;
        const int col = nt * 16 + (lane & 15), g = lane >> 4;
        #pragma unroll
        for (int e = 0; e < 8; ++e) {
            const int k = s * 32 + g * 4 + (e & 3) + 16 * (e >> 2);
            vals[e] = f2bf(W2[k * 64 + col]);
        }
        int4 v;
        v.x = vals[0] | (vals[1] << 16); v.y = vals[2] | (vals[3] << 16);
        v.z = vals[4] | (vals[5] << 16); v.w = vals[6] | (vals[7] << 16);
        W2p[i2] = v;
    }
}

__global__ __launch_bounds__(512, 6) void it_mfma_kernel(
    const float* __restrict__ y,     // [n_in][3]
    const float* __restrict__ xq,    // [n_out][3]
    const float* __restrict__ f_y,   // [n_in][64]
    const float* __restrict__ b1,    // [128]
    const float* __restrict__ b2,    // [64]
    const float* __restrict__ av,    // [128]
    const int*   __restrict__ nbr,   // [n_out*32]
    const int4*  __restrict__ Wall,  // W1p (1536) ++ W2p (1024) fragments
    float*       __restrict__ out,   // [n_out][64]
    int n_out)
{
    __shared__ int4 sW[2560];              // 40 KB: W1 frags then W2 frags

    const int tid = threadIdx.x;
    const int w   = tid >> 6;              // wave 0..7
    const int l   = tid & 63;              // lane
    const int l15 = l & 15;
    const int g   = l >> 4;                // quarter-group 0..3

    // ---- prologue (only barrier): stage packed weights into LDS ----
    #pragma unroll
    for (int t = 0; t < 5; ++t)
        sW[tid + t * 512] = Wall[tid + t * 512];
    __syncthreads();
    const int4* sW1 = sW;                  // region (mt*3+s)*64 + lane
    const int4* sW2 = sW + 1536;           // region (s2*4+nto)*64 + lane

    const f32x4 zero4 = {0.f, 0.f, 0.f, 0.f};

    const int q = blockIdx.x * WAVES + w;  // one query per wave
    if (q >= n_out) return;                // after the only barrier: safe

    // ---------- phase 1: gather edge data into per-lane B1 fragments ----
    const int ni0 = nbr[q * KNBR + l15];        // edge l15      (nt=0)
    const int ni1 = nbr[q * KNBR + 16 + l15];   // edge 16+l15   (nt=1)

    Frag B1[2][3];                     // [nt][s]
    {
        const float4* f0 = (const float4*)(f_y + (long)ni0 * 64 + g * 8);
        const float4* f1 = (const float4*)(f_y + (long)ni1 * 64 + g * 8);
        float4 a0 = f0[0], a1 = f0[1];          // s=0: cols g*8..g*8+7
        float4 a2 = f0[8], a3 = f0[9];          // s=1: cols 32+g*8..
        float4 c0 = f1[0], c1 = f1[1];
        float4 c2 = f1[8], c3 = f1[9];
        B1[0][0].i.x = cvt_pk_bf16(a0.x, a0.y);
        B1[0][0].i.y = cvt_pk_bf16(a0.z, a0.w);
        B1[0][0].i.z = cvt_pk_bf16(a1.x, a1.y);
        B1[0][0].i.w = cvt_pk_bf16(a1.z, a1.w);
        B1[0][1].i.x = cvt_pk_bf16(a2.x, a2.y);
        B1[0][1].i.y = cvt_pk_bf16(a2.z, a2.w);
        B1[0][1].i.z = cvt_pk_bf16(a3.x, a3.y);
        B1[0][1].i.w = cvt_pk_bf16(a3.z, a3.w);
        B1[1][0].i.x = cvt_pk_bf16(c0.x, c0.y);
        B1[1][0].i.y = cvt_pk_bf16(c0.z, c0.w);
        B1[1][0].i.z = cvt_pk_bf16(c1.x, c1.y);
        B1[1][0].i.w = cvt_pk_bf16(c1.z, c1.w);
        B1[1][1].i.x = cvt_pk_bf16(c2.x, c2.y);
        B1[1][1].i.y = cvt_pk_bf16(c2.z, c2.w);
        B1[1][1].i.z = cvt_pk_bf16(c3.x, c3.y);
        B1[1][1].i.w = cvt_pk_bf16(c3.z, c3.w);
    }
    // s=2 region: coords in slots 64..69 (group g==0 only), rest zero pad
    B1[0][2].i = make_int4(0, 0, 0, 0);
    B1[1][2].i = make_int4(0, 0, 0, 0);
    if (g == 0) {
        float2 ya = *(const float2*)(y + ni0 * 3);
        float  yaz = y[ni0 * 3 + 2];
        float2 yb = *(const float2*)(y + ni1 * 3);
        float  ybz = y[ni1 * 3 + 2];
        float2 x01 = *(const float2*)(xq + q * 3);
        float  xz  = xq[q * 3 + 2];
        B1[0][2].i.x = cvt_pk_bf16(ya.x, ya.y);
        B1[0][2].i.y = cvt_pk_bf16(yaz,  x01.x);
        B1[0][2].i.z = cvt_pk_bf16(x01.y, xz);
        B1[1][2].i.x = cvt_pk_bf16(yb.x, yb.y);
        B1[1][2].i.y = cvt_pk_bf16(ybz,  x01.x);
        B1[1][2].i.z = cvt_pk_bf16(x01.y, xz);
    }

    // ---------- phase 2+3: GEMM1 (per mt-pair) + gelu + pack A2 ---------
    Frag A2[2][4];                     // [nt][s2]  h as GEMM2 A-fragments
    float sc0 = 0.f, sc1 = 0.f;        // score partials (edges l15, 16+l15)
    #pragma unroll
    for (int j = 0; j < 4; ++j) {      // mt pair (2j, 2j+1)
        f32x4 acc[2][2] = {{zero4, zero4}, {zero4, zero4}};  // [mp][nt]
        #pragma unroll
        for (int s = 0; s < 3; ++s) {
            Frag wa0, wa1;
            wa0.i = sW1[((2 * j + 0) * 3 + s) * 64 + l];
            wa1.i = sW1[((2 * j + 1) * 3 + s) * 64 + l];
            acc[0][0] = __builtin_amdgcn_mfma_f32_16x16x32_bf16(wa0.b, B1[0][s].b, acc[0][0], 0, 0, 0);
            acc[0][1] = __builtin_amdgcn_mfma_f32_16x16x32_bf16(wa0.b, B1[1][s].b, acc[0][1], 0, 0, 0);
            acc[1][0] = __builtin_amdgcn_mfma_f32_16x16x32_bf16(wa1.b, B1[0][s].b, acc[1][0], 0, 0, 0);
            acc[1][1] = __builtin_amdgcn_mfma_f32_16x16x32_bf16(wa1.b, B1[1][s].b, acc[1][1], 0, 0, 0);
        }
        #pragma unroll
        for (int mp = 0; mp < 2; ++mp) {
            const int hbase = (2 * j + mp) * 16 + g * 4;
            float4 b14 = *(const float4*)(b1 + hbase);
            float4 a14 = *(const float4*)(av + hbase);
            float h0[4], h1[4];
            h0[0] = fast_gelu(acc[mp][0][0] + b14.x);
            h0[1] = fast_gelu(acc[mp][0][1] + b14.y);
            h0[2] = fast_gelu(acc[mp][0][2] + b14.z);
            h0[3] = fast_gelu(acc[mp][0][3] + b14.w);
            h1[0] = fast_gelu(acc[mp][1][0] + b14.x);
            h1[1] = fast_gelu(acc[mp][1][1] + b14.y);
            h1[2] = fast_gelu(acc[mp][1][2] + b14.z);
            h1[3] = fast_gelu(acc[mp][1][3] + b14.w);
            sc0 = fmaf(h0[0], a14.x, sc0); sc0 = fmaf(h0[1], a14.y, sc0);
            sc0 = fmaf(h0[2], a14.z, sc0); sc0 = fmaf(h0[3], a14.w, sc0);
            sc1 = fmaf(h1[0], a14.x, sc1); sc1 = fmaf(h1[1], a14.y, sc1);
            sc1 = fmaf(h1[2], a14.z, sc1); sc1 = fmaf(h1[3], a14.w, sc1);
            // A2[nt][j] words: mp=0 -> x,y ; mp=1 -> z,w
            if (mp == 0) {
                A2[0][j].i.x = cvt_pk_bf16(h0[0], h0[1]);
                A2[0][j].i.y = cvt_pk_bf16(h0[2], h0[3]);
                A2[1][j].i.x = cvt_pk_bf16(h1[0], h1[1]);
                A2[1][j].i.y = cvt_pk_bf16(h1[2], h1[3]);
            } else {
                A2[0][j].i.z = cvt_pk_bf16(h0[0], h0[1]);
                A2[0][j].i.w = cvt_pk_bf16(h0[2], h0[3]);
                A2[1][j].i.z = cvt_pk_bf16(h1[0], h1[1]);
                A2[1][j].i.w = cvt_pk_bf16(h1[2], h1[3]);
            }
        }
    }

    // ---------- phase 4: in-wave softmax over 32 edges -------------------
    sc0 += __shfl_xor(sc0, 16, 64); sc0 += __shfl_xor(sc0, 32, 64);
    sc1 += __shfl_xor(sc1, 16, 64); sc1 += __shfl_xor(sc1, 32, 64);
    float mx = fmaxf(sc0, sc1);
    mx = fmaxf(mx, __shfl_xor(mx, 1, 64));
    mx = fmaxf(mx, __shfl_xor(mx, 2, 64));
    mx = fmaxf(mx, __shfl_xor(mx, 4, 64));
    mx = fmaxf(mx, __shfl_xor(mx, 8, 64));
    float ex0 = __expf(sc0 - mx);
    float ex1 = __expf(sc1 - mx);
    float sm = ex0 + ex1;
    sm += __shfl_xor(sm, 1, 64);
    sm += __shfl_xor(sm, 2, 64);
    sm += __shfl_xor(sm, 4, 64);
    sm += __shfl_xor(sm, 8, 64);
    const float inv = __fdividef(1.0f, sm);
    const float al0 = ex0 * inv;       // alpha[edge l15]
    const float al1 = ex1 * inv;       // alpha[edge 16+l15]

    // ---------- phase 5: GEMM2, K=128 in one wave ------------------------
    f32x4 acc2[2][4] = {{zero4, zero4, zero4, zero4},
                        {zero4, zero4, zero4, zero4}};   // [nt][nto]
    #pragma unroll
    for (int s2 = 0; s2 < 4; ++s2) {
        #pragma unroll
        for (int nto = 0; nto < 4; ++nto) {
            Frag wb;
            wb.i = sW2[(s2 * 4 + nto) * 64 + l];
            acc2[0][nto] = __builtin_amdgcn_mfma_f32_16x16x32_bf16(A2[0][s2].b, wb.b, acc2[0][nto], 0, 0, 0);
            acc2[1][nto] = __builtin_amdgcn_mfma_f32_16x16x32_bf16(A2[1][s2].b, wb.b, acc2[1][nto], 0, 0, 0);
        }
    }

    // ---------- phase 6: alpha-weighted edge reduce (fp32) + store -------
    float ar0[4], ar1[4];              // alpha for C rows g*4+r (per nt)
    #pragma unroll
    for (int r = 0; r < 4; ++r) {
        ar0[r] = __shfl(al0, g * 4 + r, 64);
        ar1[r] = __shfl(al1, g * 4 + r, 64);
    }
    #pragma unroll
    for (int nto = 0; nto < 4; ++nto) {
        float o = 0.f;
        #pragma unroll
        for (int r = 0; r < 4; ++r) {
            o = fmaf(ar0[r], acc2[0][nto][r], o);
            o = fmaf(ar1[r], acc2[1][nto][r], o);
        }
        o += __shfl_xor(o, 16, 64);
        o += __shfl_xor(o, 32, 64);
        if (l < 16)
            out[q * 64 + nto * 16 + l] = o + b2[nto * 16 + l];
    }
}

extern "C" void kernel_launch(void* const* d_in, const int* in_sizes, int n_in,
                              void* d_out, int out_size, void* d_ws, size_t ws_size,
                              hipStream_t stream) {
    const float* y   = (const float*)d_in[0];
    const float* xq  = (const float*)d_in[1];
    const float* f_y = (const float*)d_in[2];
    const float* W1  = (const float*)d_in[3];
    const float* b1  = (const float*)d_in[4];
    const float* W2  = (const float*)d_in[5];
    const float* b2  = (const float*)d_in[6];
    const float* av  = (const float*)d_in[7];
    const int*   nbr = (const int*)d_in[8];
    float* out = (float*)d_out;

    const int n_out = in_sizes[1] / 3;      // x is [n_out][3]

    int4* W1p = (int4*)d_ws;                // 1536 frags = 24 KB
    int4* W2p = W1p + 1536;                 // 1024 frags = 16 KB (contiguous)

    pack_weights_kernel<<<10, 256, 0, stream>>>(W1, W2, W1p, W2p);
    const int nblk = (n_out + WAVES - 1) / WAVES;
    it_mfma_kernel<<<nblk, 512, 0, stream>>>(y, xq, f_y, b1, b2, av, nbr,
                                             W1p, out, n_out);
}

// Round 9
// 75.844 us; speedup vs baseline: 1.8997x; 1.0041x over previous
//
#include <hip/hip_runtime.h>

typedef __attribute__((ext_vector_type(8))) short bf16x8;
typedef __attribute__((ext_vector_type(4))) float f32x4;
typedef __attribute__((ext_vector_type(2))) float f32x2;

#define KNBR 32
#define WAVES 8         // waves per block, one query per wave

union Frag { int4 i; bf16x8 b; };

__device__ __forceinline__ unsigned short f2bf(float f) {
    unsigned u = __float_as_uint(f);
    u += 0x7FFFu + ((u >> 16) & 1u);          // RNE to bf16
    return (unsigned short)(u >> 16);
}

// one instruction packs two fp32 -> two bf16 (dst.lo = src0, dst.hi = src1)
__device__ __forceinline__ unsigned cvt_pk_bf16(float lo, float hi) {
    unsigned r;
    asm("v_cvt_pk_bf16_f32 %0, %1, %2" : "=v"(r) : "v"(lo), "v"(hi));
    return r;
}

// gelu_tanh(v) = v * sigmoid(2*c0*(v + c1 v^3)), vectorized 2-wide so the
// compiler emits packed v_pk_{mul,fma,add}_f32 (dual-issue fp32 on gfx950).
// Only exp/rcp are scalar trans ops.
__device__ __forceinline__ f32x2 fast_gelu2(f32x2 v) {
    const f32x2 c1v  = {0.044715f, 0.044715f};
    const f32x2 onev = {1.0f, 1.0f};
    const f32x2 K2v  = {-2.3022081951f, -2.3022081951f};  // -2*sqrt(2/pi)*log2(e)
    f32x2 p = v * __builtin_elementwise_fma(c1v, v * v, onev);
    f32x2 t = K2v * p;
    float e0, e1, r0, r1;
    asm("v_exp_f32 %0, %1" : "=v"(e0) : "v"(t.x));
    asm("v_exp_f32 %0, %1" : "=v"(e1) : "v"(t.y));
    f32x2 ev = {e0, e1};
    f32x2 d = ev + onev;
    asm("v_rcp_f32 %0, %1" : "=v"(r0) : "v"(d.x));
    asm("v_rcp_f32 %0, %1" : "=v"(r1) : "v"(d.y));
    f32x2 rv = {r0, r1};
    return v * rv;
}

// k-SLOT REMAP (slot = MFMA contraction index, logical = reference k):
//   slot 0..63  -> edge_in logical k = slot+6   (f_y[0..63], 16B-aligned gathers)
//   slot 64..69 -> edge_in logical k = slot-64  (y0 y1 y2 x0 x1 x2)
//   slot 70..95 -> zero pad
// W1 packed as A-fragments of W1^T with the same slot map:
//   region (mt 0..7, s 0..2), lane l, elem e: row = mt*16+(l&15), slot = s*32+(l>>4)*8+e
// W2 packed as B-fragments with the GEMM2 k-map matching h-in-register layout:
//   region (s 0..3, nt 0..3), lane l, elem e: col = nt*16+(l&15),
//   k = s*32 + (l>>4)*4 + (e&3) + 16*(e>>2)
__global__ __launch_bounds__(256) void pack_weights_kernel(
    const float* __restrict__ W1, const float* __restrict__ W2,
    int4* __restrict__ W1p, int4* __restrict__ W2p)
{
    const int idx = blockIdx.x * 256 + threadIdx.x;
    unsigned short vals[8];
    if (idx < 1536) {                      // 24 regions x 64 lanes
        const int r = idx >> 6, lane = idx & 63;
        const int mt = r / 3, s = r - mt * 3;
        const int row = mt * 16 + (lane & 15), g = lane >> 4;
        #pragma unroll
        for (int e = 0; e < 8; ++e) {
            const int k = s * 32 + g * 8 + e;          // slot index
            float f;
            if      (k < 64) f = W1[(k + 6) * 128 + row];   // f_y features
            else if (k < 70) f = W1[(k - 64) * 128 + row];  // y,x coords
            else             f = 0.0f;
            vals[e] = f2bf(f);
        }
        int4 v;
        v.x = vals[0] | (vals[1] << 16); v.y = vals[2] | (vals[3] << 16);
        v.z = vals[4] | (vals[5] << 16); v.w = vals[6] | (vals[7] << 16);
        W1p[idx] = v;
    } else if (idx < 2560) {               // 16 regions x 64 lanes
        const int i2 = idx - 1536;
        const int r = i2 >> 6, lane = i2 & 63;
        const int s = r >> 2, nt = r & 3;
        const int col = nt * 16 + (lane & 15), g = lane >> 4;
        #pragma unroll
        for (int e = 0; e < 8; ++e) {
            const int k = s * 32 + g * 4 + (e & 3) + 16 * (e >> 2);
            vals[e] = f2bf(W2[k * 64 + col]);
        }
        int4 v;
        v.x = vals[0] | (vals[1] << 16); v.y = vals[2] | (vals[3] << 16);
        v.z = vals[4] | (vals[5] << 16); v.w = vals[6] | (vals[7] << 16);
        W2p[i2] = v;
    }
}

__global__ __launch_bounds__(512, 6) void it_mfma_kernel(
    const float* __restrict__ y,     // [n_in][3]
    const float* __restrict__ xq,    // [n_out][3]
    const float* __restrict__ f_y,   // [n_in][64]
    const float* __restrict__ b1,    // [128]
    const float* __restrict__ b2,    // [64]
    const float* __restrict__ av,    // [128]
    const int*   __restrict__ nbr,   // [n_out*32]
    const int4*  __restrict__ Wall,  // W1p (1536) ++ W2p (1024) fragments
    float*       __restrict__ out,   // [n_out][64]
    int n_out)
{
    __shared__ int4 sW[2560];              // 40 KB: W1 frags then W2 frags

    const int tid = threadIdx.x;
    const int w   = tid >> 6;              // wave 0..7
    const int l   = tid & 63;              // lane
    const int l15 = l & 15;
    const int g   = l >> 4;                // quarter-group 0..3

    // ---- prologue (only barrier): stage packed weights into LDS ----
    #pragma unroll
    for (int t = 0; t < 5; ++t)
        sW[tid + t * 512] = Wall[tid + t * 512];
    __syncthreads();
    const int4* sW1 = sW;                  // region (mt*3+s)*64 + lane
    const int4* sW2 = sW + 1536;           // region (s2*4+nto)*64 + lane

    const f32x4 zero4 = {0.f, 0.f, 0.f, 0.f};

    const int q = blockIdx.x * WAVES + w;  // one query per wave
    if (q >= n_out) return;                // after the only barrier: safe

    // ---------- phase 1: gather edge data into per-lane B1 fragments ----
    const int ni0 = nbr[q * KNBR + l15];        // edge l15      (nt=0)
    const int ni1 = nbr[q * KNBR + 16 + l15];   // edge 16+l15   (nt=1)

    Frag B1[2][3];                     // [nt][s]
    {
        const float4* f0 = (const float4*)(f_y + (long)ni0 * 64 + g * 8);
        const float4* f1 = (const float4*)(f_y + (long)ni1 * 64 + g * 8);
        float4 a0 = f0[0], a1 = f0[1];          // s=0: cols g*8..g*8+7
        float4 a2 = f0[8], a3 = f0[9];          // s=1: cols 32+g*8..
        float4 c0 = f1[0], c1 = f1[1];
        float4 c2 = f1[8], c3 = f1[9];
        B1[0][0].i.x = cvt_pk_bf16(a0.x, a0.y);
        B1[0][0].i.y = cvt_pk_bf16(a0.z, a0.w);
        B1[0][0].i.z = cvt_pk_bf16(a1.x, a1.y);
        B1[0][0].i.w = cvt_pk_bf16(a1.z, a1.w);
        B1[0][1].i.x = cvt_pk_bf16(a2.x, a2.y);
        B1[0][1].i.y = cvt_pk_bf16(a2.z, a2.w);
        B1[0][1].i.z = cvt_pk_bf16(a3.x, a3.y);
        B1[0][1].i.w = cvt_pk_bf16(a3.z, a3.w);
        B1[1][0].i.x = cvt_pk_bf16(c0.x, c0.y);
        B1[1][0].i.y = cvt_pk_bf16(c0.z, c0.w);
        B1[1][0].i.z = cvt_pk_bf16(c1.x, c1.y);
        B1[1][0].i.w = cvt_pk_bf16(c1.z, c1.w);
        B1[1][1].i.x = cvt_pk_bf16(c2.x, c2.y);
        B1[1][1].i.y = cvt_pk_bf16(c2.z, c2.w);
        B1[1][1].i.z = cvt_pk_bf16(c3.x, c3.y);
        B1[1][1].i.w = cvt_pk_bf16(c3.z, c3.w);
    }
    // s=2 region: coords in slots 64..69 (group g==0 only), rest zero pad
    B1[0][2].i = make_int4(0, 0, 0, 0);
    B1[1][2].i = make_int4(0, 0, 0, 0);
    if (g == 0) {
        float2 ya = *(const float2*)(y + ni0 * 3);
        float  yaz = y[ni0 * 3 + 2];
        float2 yb = *(const float2*)(y + ni1 * 3);
        float  ybz = y[ni1 * 3 + 2];
        float2 x01 = *(const float2*)(xq + q * 3);
        float  xz  = xq[q * 3 + 2];
        B1[0][2].i.x = cvt_pk_bf16(ya.x, ya.y);
        B1[0][2].i.y = cvt_pk_bf16(yaz,  x01.x);
        B1[0][2].i.z = cvt_pk_bf16(x01.y, xz);
        B1[1][2].i.x = cvt_pk_bf16(yb.x, yb.y);
        B1[1][2].i.y = cvt_pk_bf16(ybz,  x01.x);
        B1[1][2].i.z = cvt_pk_bf16(x01.y, xz);
    }

    // ---------- phase 2+3: GEMM1 (per mt-pair) + packed gelu + pack A2 ------
    Frag A2[2][4];                     // [nt][s2]  h as GEMM2 A-fragments
    f32x2 sc0v = {0.f, 0.f}, sc1v = {0.f, 0.f};   // packed score partials
    #pragma unroll
    for (int j = 0; j < 4; ++j) {      // mt pair (2j, 2j+1)
        f32x4 acc[2][2] = {{zero4, zero4}, {zero4, zero4}};  // [mp][nt]
        #pragma unroll
        for (int s = 0; s < 3; ++s) {
            Frag wa0, wa1;
            wa0.i = sW1[((2 * j + 0) * 3 + s) * 64 + l];
            wa1.i = sW1[((2 * j + 1) * 3 + s) * 64 + l];
            acc[0][0] = __builtin_amdgcn_mfma_f32_16x16x32_bf16(wa0.b, B1[0][s].b, acc[0][0], 0, 0, 0);
            acc[0][1] = __builtin_amdgcn_mfma_f32_16x16x32_bf16(wa0.b, B1[1][s].b, acc[0][1], 0, 0, 0);
            acc[1][0] = __builtin_amdgcn_mfma_f32_16x16x32_bf16(wa1.b, B1[0][s].b, acc[1][0], 0, 0, 0);
            acc[1][1] = __builtin_amdgcn_mfma_f32_16x16x32_bf16(wa1.b, B1[1][s].b, acc[1][1], 0, 0, 0);
        }
        #pragma unroll
        for (int mp = 0; mp < 2; ++mp) {
            const int hbase = (2 * j + mp) * 16 + g * 4;
            float4 b14 = *(const float4*)(b1 + hbase);
            float4 a14 = *(const float4*)(av + hbase);
            f32x2 b01 = {b14.x, b14.y}, b23 = {b14.z, b14.w};
            f32x2 a01 = {a14.x, a14.y}, a23 = {a14.z, a14.w};

            f32x2 t0a = {acc[mp][0][0], acc[mp][0][1]};
            f32x2 t0b = {acc[mp][0][2], acc[mp][0][3]};
            f32x2 t1a = {acc[mp][1][0], acc[mp][1][1]};
            f32x2 t1b = {acc[mp][1][2], acc[mp][1][3]};
            f32x2 h0a = fast_gelu2(t0a + b01);
            f32x2 h0b = fast_gelu2(t0b + b23);
            f32x2 h1a = fast_gelu2(t1a + b01);
            f32x2 h1b = fast_gelu2(t1b + b23);

            sc0v = __builtin_elementwise_fma(h0a, a01, sc0v);
            sc0v = __builtin_elementwise_fma(h0b, a23, sc0v);
            sc1v = __builtin_elementwise_fma(h1a, a01, sc1v);
            sc1v = __builtin_elementwise_fma(h1b, a23, sc1v);

            // A2[nt][j] words: mp=0 -> x,y ; mp=1 -> z,w
            if (mp == 0) {
                A2[0][j].i.x = cvt_pk_bf16(h0a.x, h0a.y);
                A2[0][j].i.y = cvt_pk_bf16(h0b.x, h0b.y);
                A2[1][j].i.x = cvt_pk_bf16(h1a.x, h1a.y);
                A2[1][j].i.y = cvt_pk_bf16(h1b.x, h1b.y);
            } else {
                A2[0][j].i.z = cvt_pk_bf16(h0a.x, h0a.y);
                A2[0][j].i.w = cvt_pk_bf16(h0b.x, h0b.y);
                A2[1][j].i.z = cvt_pk_bf16(h1a.x, h1a.y);
                A2[1][j].i.w = cvt_pk_bf16(h1b.x, h1b.y);
            }
        }
    }
    float sc0 = sc0v.x + sc0v.y;
    float sc1 = sc1v.x + sc1v.y;

    // ---------- phase 4: in-wave softmax over 32 edges -------------------
    sc0 += __shfl_xor(sc0, 16, 64); sc0 += __shfl_xor(sc0, 32, 64);
    sc1 += __shfl_xor(sc1, 16, 64); sc1 += __shfl_xor(sc1, 32, 64);
    float mx = fmaxf(sc0, sc1);
    mx = fmaxf(mx, __shfl_xor(mx, 1, 64));
    mx = fmaxf(mx, __shfl_xor(mx, 2, 64));
    mx = fmaxf(mx, __shfl_xor(mx, 4, 64));
    mx = fmaxf(mx, __shfl_xor(mx, 8, 64));
    float ex0 = __expf(sc0 - mx);
    float ex1 = __expf(sc1 - mx);
    float sm = ex0 + ex1;
    sm += __shfl_xor(sm, 1, 64);
    sm += __shfl_xor(sm, 2, 64);
    sm += __shfl_xor(sm, 4, 64);
    sm += __shfl_xor(sm, 8, 64);
    const float inv = __fdividef(1.0f, sm);
    const float al0 = ex0 * inv;       // alpha[edge l15]
    const float al1 = ex1 * inv;       // alpha[edge 16+l15]

    // ---------- phase 5: GEMM2, K=128 in one wave ------------------------
    f32x4 acc2[2][4] = {{zero4, zero4, zero4, zero4},
                        {zero4, zero4, zero4, zero4}};   // [nt][nto]
    #pragma unroll
    for (int s2 = 0; s2 < 4; ++s2) {
        #pragma unroll
        for (int nto = 0; nto < 4; ++nto) {
            Frag wb;
            wb.i = sW2[(s2 * 4 + nto) * 64 + l];
            acc2[0][nto] = __builtin_amdgcn_mfma_f32_16x16x32_bf16(A2[0][s2].b, wb.b, acc2[0][nto], 0, 0, 0);
            acc2[1][nto] = __builtin_amdgcn_mfma_f32_16x16x32_bf16(A2[1][s2].b, wb.b, acc2[1][nto], 0, 0, 0);
        }
    }

    // ---------- phase 6: alpha-weighted edge reduce (packed fp32) --------
    f32x2 ar0a, ar0b, ar1a, ar1b;      // alpha for C rows g*4+r (per nt)
    ar0a.x = __shfl(al0, g * 4 + 0, 64); ar0a.y = __shfl(al0, g * 4 + 1, 64);
    ar0b.x = __shfl(al0, g * 4 + 2, 64); ar0b.y = __shfl(al0, g * 4 + 3, 64);
    ar1a.x = __shfl(al1, g * 4 + 0, 64); ar1a.y = __shfl(al1, g * 4 + 1, 64);
    ar1b.x = __shfl(al1, g * 4 + 2, 64); ar1b.y = __shfl(al1, g * 4 + 3, 64);
    #pragma unroll
    for (int nto = 0; nto < 4; ++nto) {
        f32x2 p0 = {acc2[0][nto][0], acc2[0][nto][1]};
        f32x2 p1 = {acc2[0][nto][2], acc2[0][nto][3]};
        f32x2 p2 = {acc2[1][nto][0], acc2[1][nto][1]};
        f32x2 p3 = {acc2[1][nto][2], acc2[1][nto][3]};
        f32x2 o2 = p0 * ar0a;
        o2 = __builtin_elementwise_fma(p1, ar0b, o2);
        o2 = __builtin_elementwise_fma(p2, ar1a, o2);
        o2 = __builtin_elementwise_fma(p3, ar1b, o2);
        float o = o2.x + o2.y;
        o += __shfl_xor(o, 16, 64);
        o += __shfl_xor(o, 32, 64);
        if (l < 16)
            out[q * 64 + nto * 16 + l] = o + b2[nto * 16 + l];
    }
}

extern "C" void kernel_launch(void* const* d_in, const int* in_sizes, int n_in,
                              void* d_out, int out_size, void* d_ws, size_t ws_size,
                              hipStream_t stream) {
    const float* y   = (const float*)d_in[0];
    const float* xq  = (const float*)d_in[1];
    const float* f_y = (const float*)d_in[2];
    const float* W1  = (const float*)d_in[3];
    const float* b1  = (const float*)d_in[4];
    const float* W2  = (const float*)d_in[5];
    const float* b2  = (const float*)d_in[6];
    const float* av  = (const float*)d_in[7];
    const int*   nbr = (const int*)d_in[8];
    float* out = (float*)d_out;

    const int n_out = in_sizes[1] / 3;      // x is [n_out][3]

    int4* W1p = (int4*)d_ws;                // 1536 frags = 24 KB
    int4* W2p = W1p + 1536;                 // 1024 frags = 16 KB (contiguous)

    pack_weights_kernel<<<10, 256, 0, stream>>>(W1, W2, W1p, W2p);
    const int nblk = (n_out + WAVES - 1) / WAVES;
    it_mfma_kernel<<<nblk, 512, 0, stream>>>(y, xq, f_y, b1, b2, av, nbr,
                                             W1p, out, n_out);
}